// Round 8
// baseline (228.157 us; speedup 1.0000x reference)
//
#include <hip/hip_runtime.h>

#define CRF_B 256
#define CRF_L 1024
#define CRF_T 128
#define WS_STRIDE 260   // floats per batch: xf[128], xb[128], kf, kb, gold

typedef __attribute__((ext_vector_type(8))) short bf16x8;
typedef __attribute__((ext_vector_type(4))) float f32x4;
typedef __attribute__((ext_vector_type(2))) short short2v;

#define MF(a, b, cacc) __builtin_amdgcn_mfma_f32_16x16x32_bf16((a), (b), (cacc), 0, 0, 0)
// LDS-visibility barrier WITHOUT vmcnt drain (global prefetches stay in flight)
#define WG_BARRIER() asm volatile("s_waitcnt lgkmcnt(0)\n\ts_barrier" ::: "memory")

static __device__ __forceinline__ unsigned short f2bf(float x) {
    union { float f; unsigned u; } v; v.f = x;
    unsigned r = v.u + 0x7FFFu + ((v.u >> 16) & 1u);   // RNE
    return (unsigned short)(r >> 16);
}
static __device__ __forceinline__ short2v bmax2(short2v a, short2v b) {
    return __builtin_elementwise_max(a, b);   // v_pk_max_i16; bf16>=0 order-preserving
}
static __device__ __forceinline__ short2v fragmax(bf16x8 a) {
    short2v q0 = __builtin_shufflevector(a, a, 0, 1);
    short2v q1 = __builtin_shufflevector(a, a, 2, 3);
    short2v q2 = __builtin_shufflevector(a, a, 4, 5);
    short2v q3 = __builtin_shufflevector(a, a, 6, 7);
    return bmax2(bmax2(q0, q1), bmax2(q2, q3));
}

// One recurrence step. Only D row 0 is consumed, and MFMA rows are
// independent, so only A row 0 (lanes with c==0: {0,16,32,48}) needs real
// fragment data -> exec-masked ds_reads (64B delivered instead of 1KB).
// Writes/loads masked to lanes 0-15 (g==0). nrm via fragmax in c==0 lanes +
// 2 shuffles + readfirstlane (SGPR broadcast). Prefetch distance 4.
#define STEP(S, P0, P1, NORM) do {                                             \
    const int sl_ = (S) & 1;                                                   \
    if (g == 0) {                                                              \
        float v0_ = isf ? x0 : F0 * x0;                                        \
        float v1_ = isf ? x1 : F1 * x1;                                        \
        s_e[sl_][c0] = f2bf(v0_); s_e[sl_][c1] = f2bf(v1_);                    \
    }                                                                          \
    WG_BARRIER();                                                              \
    if (c == 0) {                                                              \
        A0_ = *(const bf16x8*)&s_e[sl_][ 0 + 8 * g];                           \
        A1_ = *(const bf16x8*)&s_e[sl_][32 + 8 * g];                           \
        A2_ = *(const bf16x8*)&s_e[sl_][64 + 8 * g];                           \
        A3_ = *(const bf16x8*)&s_e[sl_][96 + 8 * g];                           \
    }                                                                          \
    f32x4 dA0_ = MF(A0_, Bf[0][0], Z);  f32x4 dB0_ = MF(A1_, Bf[0][1], Z);     \
    f32x4 dA1_ = MF(A0_, Bf[1][0], Z);  f32x4 dB1_ = MF(A1_, Bf[1][1], Z);     \
    dA0_ = MF(A2_, Bf[0][2], dA0_);  dB0_ = MF(A3_, Bf[0][3], dB0_);           \
    dA1_ = MF(A2_, Bf[1][2], dA1_);  dB1_ = MF(A3_, Bf[1][3], dB1_);           \
    float d0_ = dA0_[0] + dB0_[0];                                             \
    float d1_ = dA1_[0] + dB1_[0];                                             \
    if (NORM) {                                                                \
        float fm_ = 0.0f;                                                      \
        if (c == 0) {                                                          \
            short2v mx_ = bmax2(bmax2(fragmax(A0_), fragmax(A1_)),             \
                                bmax2(fragmax(A2_), fragmax(A3_)));            \
            unsigned mu_ = __builtin_bit_cast(unsigned, mx_);                  \
            fm_ = fmaxf(__builtin_bit_cast(float, mu_ << 16),                  \
                        __builtin_bit_cast(float, mu_ & 0xFFFF0000u));         \
            fm_ = fmaxf(fm_, __shfl_xor(fm_, 16, 64));                         \
            fm_ = fmaxf(fm_, __shfl_xor(fm_, 32, 64));                         \
        }                                                                      \
        float nrm_ = __builtin_bit_cast(float,                                 \
            __builtin_amdgcn_readfirstlane(__builtin_bit_cast(int, fm_)));     \
        float sig_ = __builtin_amdgcn_rcpf(nrm_);                              \
        kap += __logf(nrm_);                                                   \
        d0_ *= sig_; d1_ *= sig_;                                              \
    }                                                                          \
    x0 = isf ? F0 * d0_ : d0_;                                                 \
    x1 = isf ? F1 * d1_ : d1_;                                                 \
    F0 = __expf(P0); F1 = __expf(P1);                                          \
    if (g == 0) {                                                              \
        int rr_ = isf ? ((S) + 5) : (len - (S) - 5);                           \
        if (rr_ > CRF_L - 1) rr_ = CRF_L - 1;                                  \
        if (rr_ < 0) rr_ = 0;                                                  \
        P0 = fb[(size_t)rr_ * CRF_T + c0];                                     \
        P1 = fb[(size_t)rr_ * CRF_T + c1];                                     \
    }                                                                          \
} while (0)

// 512 blocks x 256 threads: block = one direction of one batch.
// blockIdx: b = x>>1, dir = x&1 (0 = fwd a-chain, 1 = bwd b-chain).
__global__ __launch_bounds__(256, 2) void forward_kernel(
    const float* __restrict__ trans, const float* __restrict__ feats,
    const int* __restrict__ mask, const int* __restrict__ tags,
    float* __restrict__ ws)
{
    const int b    = blockIdx.x >> 1;
    const int dir  = blockIdx.x & 1;
    const bool isf = (dir == 0);
    const int t    = threadIdx.x;
    const int w    = t >> 6;
    const int lane = t & 63;
    const int g    = lane >> 4;
    const int c    = lane & 15;
    const int c0   = 32 * w + c;
    const int c1   = c0 + 16;

    __shared__ __align__(16) unsigned short s_e[2][CRF_T];
    __shared__ float s_gold;
    __shared__ int   s_len;

    if (t == 0) { s_len = 0; s_gold = 0.0f; }
    __syncthreads();

    // ---- per-batch length (+ gold score, fwd block only) ----
    {
        int cnt = 0; float gsum = 0.0f;
        const int base = b * CRF_L;
        for (int l = t; l < CRF_L; l += 256) {
            if (mask[base + l] != 0) {
                cnt++;
                if (isf) {
                    int tg = tags[base + l];
                    float gv = feats[(size_t)(base + l) * CRF_T + tg];
                    if (l > 0) gv += trans[tags[base + l - 1] * CRF_T + tg];
                    gsum += gv;
                }
            }
        }
        for (int off = 32; off > 0; off >>= 1) {
            cnt  += __shfl_down(cnt, off, 64);
            gsum += __shfl_down(gsum, off, 64);
        }
        if (lane == 0) { atomicAdd(&s_len, cnt); if (isf) atomicAdd(&s_gold, gsum); }
    }

    // ---- B fragments: fwd = E[k][col], bwd = E[col][k] (one-time) ----
    bf16x8 Bf[2][4];
#pragma unroll
    for (int t2 = 0; t2 < 2; ++t2) {
        const int col = t2 ? c1 : c0;
#pragma unroll
        for (int kt = 0; kt < 4; ++kt)
#pragma unroll
            for (int e = 0; e < 8; ++e) {
                int k = 32 * kt + 8 * g + e;
                int idx = isf ? (k * CRF_T + col) : (col * CRF_T + k);
                Bf[t2][kt][e] = (short)f2bf(__expf(trans[idx]));
            }
    }

    __syncthreads();
    const int len    = s_len;
    const int m      = len >> 1;               // fwd steps
    const int nsteps = isf ? m : (len - 1 - m);

    const float* fb = feats + (size_t)b * CRF_L * CRF_T;

    float x0, x1, F0, F1;
    float pfA0, pfA1, pfB0, pfB1, pfC0, pfC1, pfD0, pfD1;
    float kap = 0.0f;
    if (isf) {
        x0 = __expf(fb[c0]);  x1 = __expf(fb[c1]);          // a_0 = exp(f_0)
        F0 = __expf(fb[CRF_T + c0]);  F1 = __expf(fb[CRF_T + c1]);
        pfA0 = fb[2 * CRF_T + c0];  pfA1 = fb[2 * CRF_T + c1];
        pfB0 = fb[3 * CRF_T + c0];  pfB1 = fb[3 * CRF_T + c1];
        pfC0 = fb[4 * CRF_T + c0];  pfC1 = fb[4 * CRF_T + c1];
        pfD0 = fb[5 * CRF_T + c0];  pfD1 = fb[5 * CRF_T + c1];
    } else {
        x0 = 1.0f;  x1 = 1.0f;                              // b_{len-1} = 1
        F0 = __expf(fb[(size_t)(len - 1) * CRF_T + c0]);
        F1 = __expf(fb[(size_t)(len - 1) * CRF_T + c1]);
        pfA0 = fb[(size_t)(len - 2) * CRF_T + c0];
        pfA1 = fb[(size_t)(len - 2) * CRF_T + c1];
        pfB0 = fb[(size_t)(len - 3) * CRF_T + c0];
        pfB1 = fb[(size_t)(len - 3) * CRF_T + c1];
        pfC0 = fb[(size_t)(len - 4) * CRF_T + c0];
        pfC1 = fb[(size_t)(len - 4) * CRF_T + c1];
        pfD0 = fb[(size_t)(len - 5) * CRF_T + c0];
        pfD1 = fb[(size_t)(len - 5) * CRF_T + c1];
    }

    const f32x4 Z = {};
    bf16x8 A0_ = {}, A1_ = {}, A2_ = {}, A3_ = {};   // loop-carried; masked loads

    int s = 1;
    for (; s + 3 <= nsteps; s += 4) {
        STEP(s,     pfA0, pfA1, true);
        STEP(s + 1, pfB0, pfB1, false);
        STEP(s + 2, pfC0, pfC1, true);
        STEP(s + 3, pfD0, pfD1, false);
    }
    if (s <= nsteps) { STEP(s, pfA0, pfA1, true);  s++; }
    if (s <= nsteps) { STEP(s, pfB0, pfB1, false); s++; }
    if (s <= nsteps) { STEP(s, pfC0, pfC1, true); }

    // ---- write this half-chain's state to workspace ----
    float* wsb = ws + (size_t)b * WS_STRIDE;
    if (g == 0) {
        wsb[dir * 128 + c0] = x0;
        wsb[dir * 128 + c1] = x1;
    }
    if (t == 0) {
        wsb[256 + dir] = kap;
        if (isf) wsb[258] = s_gold;
    }
}

// single block, thread t = batch t: loss_b = kf+kb+log(sum xf.xb) - gold
__global__ __launch_bounds__(256) void combine_kernel(
    const float* __restrict__ ws, float* __restrict__ out)
{
    const int t    = threadIdx.x;
    const int lane = t & 63;
    const int w    = t >> 6;
    const float4* pf = (const float4*)(ws + (size_t)t * WS_STRIDE);
    const float4* pb = pf + 32;
    float dot = 0.0f;
#pragma unroll
    for (int k = 0; k < 32; ++k) {
        float4 a = pf[k], bb = pb[k];
        dot += a.x * bb.x + a.y * bb.y + a.z * bb.z + a.w * bb.w;
    }
    const float* ps = ws + (size_t)t * WS_STRIDE;
    float val = ps[256] + ps[257] + __logf(dot) - ps[258];
    for (int off = 32; off > 0; off >>= 1) val += __shfl_down(val, off, 64);
    __shared__ float sw[4];
    if (lane == 0) sw[w] = val;
    __syncthreads();
    if (t == 0) out[0] = sw[0] + sw[1] + sw[2] + sw[3];
}

extern "C" void kernel_launch(void* const* d_in, const int* in_sizes, int n_in,
                              void* d_out, int out_size, void* d_ws, size_t ws_size,
                              hipStream_t stream) {
    const float* trans = (const float*)d_in[0];
    const float* feats = (const float*)d_in[1];
    const int*   mask  = (const int*)d_in[2];
    const int*   tags  = (const int*)d_in[3];
    float*       out   = (float*)d_out;
    float*       ws    = (float*)d_ws;

    hipLaunchKernelGGL(forward_kernel, dim3(2 * CRF_B), dim3(256), 0, stream,
                       trans, feats, mask, tags, ws);
    hipLaunchKernelGGL(combine_kernel, dim3(1), dim3(256), 0, stream, ws, out);
}